// Round 1
// baseline (2805.699 us; speedup 1.0000x reference)
//
#include <hip/hip_runtime.h>
#include <hip/hip_bf16.h>
#include <math.h>

// GraphLSTM (binary TreeLSTM), 64 trees x 2047 nodes, H=E=256, C=104.
// Round 0: correct fp32 implementation. Per-level fused kernel:
//   gather emb -> LDS, iou = X@W_iou^T + Hsum@U_iou^T + b, forget gates,
//   LSTM cell, ping-pong level buffers, incremental tree-mean via atomics.
// Children of compact row m (level l) are rows 2m,2m+1 (level l+1).

#define NTREES 64
#define TDEPTH 11
#define NPT    2047
#define HD     256
#define ED     256
#define H3     768
#define NCLS   104
#define TM     16   // nodes per block

__device__ __forceinline__ float sigmoidf_(float x) {
    return 1.0f / (1.0f + __expf(-x));
}

// Transpose weights once per call so per-j weight rows are lane-coalesced.
// Wt[j][k] = W_iou[k][j]  (Wt: [256][768]), same for Ut; Uft: [256][256].
__global__ __launch_bounds__(256) void transpose_prep(
    const float* __restrict__ W_iou, const float* __restrict__ U_iou,
    const float* __restrict__ U_f_w,
    float* __restrict__ Wt, float* __restrict__ Ut, float* __restrict__ Uft)
{
    int idx = blockIdx.x * 256 + threadIdx.x;   // 0 .. 768*256-1
    int k = idx >> 8;      // output row index (0..767)
    int j = idx & 255;     // input col (0..255)
    Wt[j * H3 + k] = W_iou[idx];
    Ut[j * H3 + k] = U_iou[idx];
    if (idx < HD * HD) {
        Uft[j * HD + k] = U_f_w[idx];
    }
}

// One level, bottom-up. 256 threads, TM nodes per block.
// Thread t owns iou columns {t, t+256, t+512} == (i,o,u) for h-channel t.
template<bool LEAF>
__global__ __launch_bounds__(256, 2) void level_kernel(
    const int*   __restrict__ feat, const float* __restrict__ emb,
    const float* __restrict__ Wt,   const float* __restrict__ Ut,
    const float* __restrict__ b_iou, const float* __restrict__ Uft,
    const float* __restrict__ U_f_b,
    const float* __restrict__ h_prev, const float* __restrict__ c_prev,
    float* __restrict__ h_cur, float* __restrict__ c_cur,
    float* __restrict__ hsum, int level)
{
    extern __shared__ float smem[];
    float* X   = smem;                // [TM][HD]
    float* Hch = smem + TM * HD;      // [2*TM][HD]   (internal only)
    float* Hs  = smem + 3 * TM * HD;  // [TM][HD]     (internal only)

    const int tid = threadIdx.x;
    const int m0  = blockIdx.x * TM;
    const int L   = 1 << level;

    // ---- stage X = emb[features] (one coalesced row per n) ----
    #pragma unroll
    for (int n = 0; n < TM; ++n) {
        const int m    = m0 + n;
        const int tree = m >> level;
        const int pos  = m - (tree << level);
        const int g    = tree * NPT + (L - 1) + pos;
        const int f    = feat[g];
        X[n * HD + tid] = emb[(size_t)f * ED + tid];
    }
    if constexpr (!LEAF) {
        #pragma unroll
        for (int r = 0; r < 2 * TM; ++r) {
            Hch[r * HD + tid] = h_prev[(size_t)(2 * m0 + r) * HD + tid];
        }
    }
    __syncthreads();
    if constexpr (!LEAF) {
        #pragma unroll
        for (int n = 0; n < TM; ++n) {
            Hs[n * HD + tid] = Hch[2 * n * HD + tid] + Hch[(2 * n + 1) * HD + tid];
        }
        __syncthreads();
    }

    // ---- Phase A: iou = X @ W_iou^T  (cols tid, tid+256, tid+512) ----
    float ai[TM], ao[TM], au[TM];
    #pragma unroll
    for (int n = 0; n < TM; ++n) { ai[n] = 0.f; ao[n] = 0.f; au[n] = 0.f; }

    for (int j = 0; j < HD; j += 4) {
        float wv[4][3];
        #pragma unroll
        for (int q = 0; q < 4; ++q) {
            #pragma unroll
            for (int c = 0; c < 3; ++c)
                wv[q][c] = Wt[(j + q) * H3 + c * 256 + tid];
        }
        #pragma unroll
        for (int n = 0; n < TM; ++n) {
            const float4 x = *reinterpret_cast<const float4*>(&X[n * HD + j]);
            ai[n] = fmaf(x.w, wv[3][0], fmaf(x.z, wv[2][0], fmaf(x.y, wv[1][0], fmaf(x.x, wv[0][0], ai[n]))));
            ao[n] = fmaf(x.w, wv[3][1], fmaf(x.z, wv[2][1], fmaf(x.y, wv[1][1], fmaf(x.x, wv[0][1], ao[n]))));
            au[n] = fmaf(x.w, wv[3][2], fmaf(x.z, wv[2][2], fmaf(x.y, wv[1][2], fmaf(x.x, wv[0][2], au[n]))));
        }
    }

    // ---- Phase B: iou += Hsum @ U_iou^T ----
    if constexpr (!LEAF) {
        for (int j = 0; j < HD; j += 4) {
            float wv[4][3];
            #pragma unroll
            for (int q = 0; q < 4; ++q) {
                #pragma unroll
                for (int c = 0; c < 3; ++c)
                    wv[q][c] = Ut[(j + q) * H3 + c * 256 + tid];
            }
            #pragma unroll
            for (int n = 0; n < TM; ++n) {
                const float4 x = *reinterpret_cast<const float4*>(&Hs[n * HD + j]);
                ai[n] = fmaf(x.w, wv[3][0], fmaf(x.z, wv[2][0], fmaf(x.y, wv[1][0], fmaf(x.x, wv[0][0], ai[n]))));
                ao[n] = fmaf(x.w, wv[3][1], fmaf(x.z, wv[2][1], fmaf(x.y, wv[1][1], fmaf(x.x, wv[0][1], ao[n]))));
                au[n] = fmaf(x.w, wv[3][2], fmaf(x.z, wv[2][2], fmaf(x.y, wv[1][2], fmaf(x.x, wv[0][2], au[n]))));
            }
        }
    }

    // ---- Phase C: forget preactivations for 2*TM child rows (col tid) ----
    float fc[2 * TM];
    if constexpr (!LEAF) {
        #pragma unroll
        for (int r = 0; r < 2 * TM; ++r) fc[r] = 0.f;
        for (int j = 0; j < HD; j += 4) {
            float w[4];
            #pragma unroll
            for (int q = 0; q < 4; ++q) w[q] = Uft[(j + q) * HD + tid];
            #pragma unroll
            for (int r = 0; r < 2 * TM; ++r) {
                const float4 x = *reinterpret_cast<const float4*>(&Hch[r * HD + j]);
                fc[r] = fmaf(x.w, w[3], fmaf(x.z, w[2], fmaf(x.y, w[1], fmaf(x.x, w[0], fc[r]))));
            }
        }
    }

    // ---- epilogue: LSTM cell + stores + incremental tree-sum ----
    const float bi = b_iou[tid];
    const float bo = b_iou[256 + tid];
    const float bu = b_iou[512 + tid];
    float fb = 0.f;
    if constexpr (!LEAF) fb = U_f_b[tid];

    float hacc = 0.f;
    int cur_tree = m0 >> level;
    #pragma unroll
    for (int n = 0; n < TM; ++n) {
        const int m = m0 + n;
        const float iv = sigmoidf_(ai[n] + bi);
        const float ov = sigmoidf_(ao[n] + bo);
        const float uv = tanhf(au[n] + bu);
        float cin = 0.f;
        if constexpr (!LEAF) {
            const float cl = c_prev[(size_t)(2 * m) * HD + tid];
            const float cr = c_prev[(size_t)(2 * m + 1) * HD + tid];
            const float fl = sigmoidf_(fc[2 * n] + fb);
            const float fr = sigmoidf_(fc[2 * n + 1] + fb);
            cin = fmaf(fl, cl, fr * cr);
        }
        const float cn = fmaf(iv, uv, cin);
        const float hn = ov * tanhf(cn);
        h_cur[(size_t)m * HD + tid] = hn;
        c_cur[(size_t)m * HD + tid] = cn;

        const int tr = m >> level;   // wave-uniform
        if (tr != cur_tree) {
            atomicAdd(&hsum[cur_tree * HD + tid], hacc);
            hacc = 0.f;
            cur_tree = tr;
        }
        hacc += hn;
    }
    atomicAdd(&hsum[cur_tree * HD + tid], hacc);
}

// out[tree][c] = (hsum[tree]/NPT) . lin_w[c] + lin_b[c]
__global__ __launch_bounds__(128) void final_kernel(
    const float* __restrict__ hsum, const float* __restrict__ lin_w,
    const float* __restrict__ lin_b, float* __restrict__ out)
{
    __shared__ float hg[HD];
    const int tree = blockIdx.x;
    for (int j = threadIdx.x; j < HD; j += 128)
        hg[j] = hsum[tree * HD + j] * (1.0f / (float)NPT);
    __syncthreads();
    const int c = threadIdx.x;
    if (c < NCLS) {
        const float* wr = lin_w + (size_t)c * HD;
        float acc = lin_b[c];
        #pragma unroll 4
        for (int j = 0; j < HD; ++j)
            acc = fmaf(hg[j], wr[j], acc);
        out[tree * NCLS + c] = acc;
    }
}

extern "C" void kernel_launch(void* const* d_in, const int* in_sizes, int n_in,
                              void* d_out, int out_size, void* d_ws, size_t ws_size,
                              hipStream_t stream)
{
    const int*   feat  = (const int*)d_in[0];
    const float* emb   = (const float*)d_in[1];
    const float* W_iou = (const float*)d_in[2];
    const float* U_iou = (const float*)d_in[3];
    const float* b_iou = (const float*)d_in[4];
    const float* U_f_w = (const float*)d_in[5];
    const float* U_f_b = (const float*)d_in[6];
    const float* lin_w = (const float*)d_in[7];
    const float* lin_b = (const float*)d_in[8];
    float* out = (float*)d_out;

    // workspace layout (all fp32): transposed weights, tree h-sum, ping-pong
    // level buffers (slot A: 65536 rows for levels 10,8,...; slot B: 32768).
    char* ws = (char*)d_ws;
    size_t off = 0;
    auto alloc = [&](size_t bytes) -> void* {
        void* p = ws + off;
        off += (bytes + 255) & ~(size_t)255;
        return p;
    };
    float* Wt   = (float*)alloc((size_t)H3 * HD * 4);
    float* Ut   = (float*)alloc((size_t)H3 * HD * 4);
    float* Uft  = (float*)alloc((size_t)HD * HD * 4);
    float* hsum = (float*)alloc((size_t)NTREES * HD * 4);
    float* hA   = (float*)alloc((size_t)65536 * HD * 4);
    float* cA   = (float*)alloc((size_t)65536 * HD * 4);
    float* hB   = (float*)alloc((size_t)32768 * HD * 4);
    float* cB   = (float*)alloc((size_t)32768 * HD * 4);
    (void)ws_size; (void)in_sizes; (void)n_in; (void)out_size;

    hipMemsetAsync(hsum, 0, (size_t)NTREES * HD * 4, stream);
    transpose_prep<<<H3, 256, 0, stream>>>(W_iou, U_iou, U_f_w, Wt, Ut, Uft);

    for (int l = TDEPTH - 1; l >= 0; --l) {
        const int M      = NTREES << l;
        const int blocks = M / TM;
        const int p      = (TDEPTH - 1 - l) & 1;   // 0 -> slot A, 1 -> slot B
        float* hc = p ? hB : hA;
        float* cc = p ? cB : cA;
        const float* hp = p ? hA : hB;
        const float* cp = p ? cA : cB;
        if (l == TDEPTH - 1) {
            level_kernel<true><<<blocks, 256, (size_t)TM * HD * 4, stream>>>(
                feat, emb, Wt, Ut, b_iou, Uft, U_f_b,
                nullptr, nullptr, hc, cc, hsum, l);
        } else {
            level_kernel<false><<<blocks, 256, (size_t)4 * TM * HD * 4, stream>>>(
                feat, emb, Wt, Ut, b_iou, Uft, U_f_b,
                hp, cp, hc, cc, hsum, l);
        }
    }

    final_kernel<<<NTREES, 128, 0, stream>>>(hsum, lin_w, lin_b, out);
}

// Round 2
// 704.523 us; speedup vs baseline: 3.9824x; 3.9824x over previous
//
#include <hip/hip_runtime.h>
#include <math.h>

// GraphLSTM (binary TreeLSTM), 64 trees x 2047 nodes, H=E=256, C=104.
// Round 1: bf16 MFMA for all matmuls (fp32 acc, fp32 c/gates/mean path).
//   Per level: BM=64 nodes/block, 8 waves. Unified K=512 GEMM
//   iou = [X | Hsum] @ [W_iou | U_iou]^T via Xcat LDS; f-gate GEMM over the
//   128 child rows; child-pair reduction register-local (D rows 4g..4g+3),
//   c_in exchanged via f32 LDS overlay on the Hch region.

#define NTREES 64
#define TDEPTH 11
#define NPT    2047
#define HD     256
#define H3     768
#define NCLS   104

typedef short v8s __attribute__((ext_vector_type(8)));
typedef float v4f __attribute__((ext_vector_type(4)));
typedef unsigned short u16;
typedef unsigned int   u32;

__device__ __forceinline__ float bf2f(u16 s) {
    u32 u = ((u32)s) << 16;
    return __builtin_bit_cast(float, u);
}
__device__ __forceinline__ u16 f2bf(float f) {
    u32 u = __builtin_bit_cast(u32, f);
    u = (u + 0x7FFFu + ((u >> 16) & 1u)) >> 16;
    return (u16)u;
}
__device__ __forceinline__ u32 pack2bf(float lo, float hi) {
    return (u32)f2bf(lo) | ((u32)f2bf(hi) << 16);
}
__device__ __forceinline__ float sigmoidf_(float x) {
    return 1.0f / (1.0f + __expf(-x));
}
__device__ __forceinline__ float tanhf_(float x) {
    x = fminf(fmaxf(x, -15.0f), 15.0f);
    float e = __expf(2.0f * x);
    return (e - 1.0f) / (e + 1.0f);
}

// Wcat[j][0:256]=W_iou[j][:], Wcat[j][256:512]=U_iou[j][:]  (bf16, row-major
// by output index -> B-frag loads are plain 16B row reads). Uf[256][256] bf16.
__global__ __launch_bounds__(256) void prep_weights(
    const float* __restrict__ W_iou, const float* __restrict__ U_iou,
    const float* __restrict__ U_f_w,
    u16* __restrict__ Wcat, u16* __restrict__ Uf)
{
    int tid = blockIdx.x * 256 + threadIdx.x;   // 0..196607
    int j  = tid >> 8;
    int c0 = (tid & 255) * 2;
    float a, b;
    if (c0 < 256) { a = W_iou[j * 256 + c0];       b = W_iou[j * 256 + c0 + 1]; }
    else          { a = U_iou[j * 256 + c0 - 256]; b = U_iou[j * 256 + c0 - 255]; }
    Wcat[j * 512 + c0]     = f2bf(a);
    Wcat[j * 512 + c0 + 1] = f2bf(b);
    if (tid < 32768) {
        int jj = tid >> 7, cc = (tid & 127) * 2;
        Uf[jj * 256 + cc]     = f2bf(U_f_w[jj * 256 + cc]);
        Uf[jj * 256 + cc + 1] = f2bf(U_f_w[jj * 256 + cc + 1]);
    }
}

// One level. 512 threads = 8 waves. Block covers 64 nodes (m0..m0+63).
// GEMM1: [64, 768] = Xcat[64,512] @ Wcat^T   (leaf: K=256, X only)
// GEMM2: [128, 256] = Hch[128,256] @ Uf^T    (forget preactivations)
template<bool LEAF>
__global__ __launch_bounds__(512, 2) void level_kernel(
    const int* __restrict__ feat, const float* __restrict__ emb,
    const u16* __restrict__ Wcat, const u16* __restrict__ Uf,
    const float* __restrict__ b_iou, const float* __restrict__ U_f_b,
    const u16* __restrict__ h_prev, const float* __restrict__ c_prev,
    u16* __restrict__ h_cur, float* __restrict__ c_cur,
    float* __restrict__ hsum, int level)
{
    constexpr int XS = LEAF ? 264 : 520;     // xcat row stride (bf16 elems)
    __shared__ u16 xcat[64 * XS];
    __shared__ u16 hch_s[LEAF ? 8 : 128 * 264];

    const int tid = threadIdx.x;
    const int wv  = tid >> 6;       // wave 0..7
    const int ln  = tid & 63;
    const int g   = ln >> 4;        // lane group 0..3
    const int r15 = ln & 15;
    const int m0  = blockIdx.x * 64;
    const int L   = 1 << level;

    // ---- stage X = bf16(emb[features]) : wave w stages rows 8w..8w+7 ----
    int fidx[8];
    #pragma unroll
    for (int it = 0; it < 8; ++it) {
        const int m    = m0 + wv * 8 + it;
        const int tree = m >> level;
        const int pos  = m & (L - 1);
        fidx[it] = feat[tree * NPT + (L - 1) + pos];
    }
    #pragma unroll
    for (int it = 0; it < 8; ++it) {
        const int r = wv * 8 + it;
        const float4 v = *(const float4*)(emb + (size_t)fidx[it] * HD + ln * 4);
        uint2 o;
        o.x = pack2bf(v.x, v.y);
        o.y = pack2bf(v.z, v.w);
        *(uint2*)&xcat[r * XS + ln * 4] = o;
    }

    // ---- stage Hch (128 child rows of bf16 h_prev) ----
    if constexpr (!LEAF) {
        #pragma unroll
        for (int it = 0; it < 8; ++it) {
            const int r = wv * 16 + it * 2 + (ln >> 5);
            v8s hv = *(const v8s*)(h_prev + (size_t)(2 * m0 + r) * HD + (ln & 31) * 8);
            *(v8s*)&hch_s[r * 264 + (ln & 31) * 8] = hv;
        }
    }
    __syncthreads();

    // ---- Hsum -> Xcat[:,256:512]  and  GEMM2 (forget gates) ----
    v4f acc2[2][8];
    if constexpr (!LEAF) {
        #pragma unroll
        for (int it = 0; it < 8; ++it) {
            const int r = wv * 8 + it;
            const uint2 a = *(const uint2*)&hch_s[(2 * r) * 264 + ln * 4];
            const uint2 b = *(const uint2*)&hch_s[(2 * r + 1) * 264 + ln * 4];
            uint2 o;
            o.x = pack2bf(bf2f(a.x & 0xffff) + bf2f(b.x & 0xffff),
                          bf2f(a.x >> 16)    + bf2f(b.x >> 16));
            o.y = pack2bf(bf2f(a.y & 0xffff) + bf2f(b.y & 0xffff),
                          bf2f(a.y >> 16)    + bf2f(b.y >> 16));
            *(uint2*)&xcat[r * XS + 256 + ln * 4] = o;
        }

        #pragma unroll
        for (int nt = 0; nt < 2; ++nt)
            #pragma unroll
            for (int mt = 0; mt < 8; ++mt)
                acc2[nt][mt] = (v4f){0.f, 0.f, 0.f, 0.f};

        for (int ks = 0; ks < 8; ++ks) {
            v8s a2[8];
            #pragma unroll
            for (int mt = 0; mt < 8; ++mt)
                a2[mt] = *(const v8s*)&hch_s[(16 * mt + r15) * 264 + ks * 32 + g * 8];
            #pragma unroll
            for (int nt = 0; nt < 2; ++nt) {
                const int n = wv + 8 * nt;
                v8s b = *(const v8s*)(Uf + (size_t)(16 * n + r15) * 256 + ks * 32 + g * 8);
                #pragma unroll
                for (int mt = 0; mt < 8; ++mt)
                    acc2[nt][mt] = __builtin_amdgcn_mfma_f32_16x16x32_bf16(
                        a2[mt], b, acc2[nt][mt], 0, 0, 0);
            }
        }
    }
    __syncthreads();   // all Hch LDS reads done; Hsum visible

    // ---- f-epilogue: c_in = f_l*c_l + f_r*c_r -> f32 LDS over Hch ----
    float* cin = (float*)hch_s;   // [64][264] f32 (same bytes as Hch)
    if constexpr (!LEAF) {
        #pragma unroll
        for (int nt = 0; nt < 2; ++nt) {
            const int ch = 16 * (wv + 8 * nt) + r15;
            const float fb = U_f_b[ch];
            #pragma unroll
            for (int mt = 0; mt < 8; ++mt) {
                float ps = 0.f;
                #pragma unroll
                for (int r = 0; r < 4; ++r) {
                    const int cr = 16 * mt + 4 * g + r;
                    const float f = sigmoidf_(acc2[nt][mt][r] + fb);
                    const float cp = c_prev[(size_t)(2 * m0 + cr) * HD + ch];
                    ps = (r & 1) ? (ps + f * cp) : (f * cp);
                    if (r & 1) cin[(8 * mt + 2 * g + (r >> 1)) * 264 + ch] = ps;
                }
            }
        }
    }

    // ---- GEMM1: iou (wave w owns N-tiles {w+8t}, t=0..5) ----
    v4f acc1[6][4];
    #pragma unroll
    for (int t = 0; t < 6; ++t)
        #pragma unroll
        for (int mt = 0; mt < 4; ++mt)
            acc1[t][mt] = (v4f){0.f, 0.f, 0.f, 0.f};

    constexpr int KS1 = LEAF ? 8 : 16;
    for (int ks = 0; ks < KS1; ++ks) {
        v8s a1[4];
        #pragma unroll
        for (int mt = 0; mt < 4; ++mt)
            a1[mt] = *(const v8s*)&xcat[(16 * mt + r15) * XS + ks * 32 + g * 8];
        #pragma unroll
        for (int t = 0; t < 6; ++t) {
            const int n = wv + 8 * t;
            v8s b = *(const v8s*)(Wcat + (size_t)(16 * n + r15) * 512 + ks * 32 + g * 8);
            #pragma unroll
            for (int mt = 0; mt < 4; ++mt)
                acc1[t][mt] = __builtin_amdgcn_mfma_f32_16x16x32_bf16(
                    a1[mt], b, acc1[t][mt], 0, 0, 0);
        }
    }
    __syncthreads();   // cin writes visible

    // ---- final epilogue: LSTM cell, stores, tree-mean accumulation ----
    #pragma unroll
    for (int p = 0; p < 2; ++p) {
        const int ch = 16 * (wv + 8 * p) + r15;
        const float bi = b_iou[ch];
        const float bo = b_iou[256 + ch];
        const float bu = b_iou[512 + ch];
        float hacc = 0.f;
        #pragma unroll
        for (int mt = 0; mt < 4; ++mt) {
            #pragma unroll
            for (int r = 0; r < 4; ++r) {
                const int ml = 16 * mt + 4 * g + r;
                const float iv = sigmoidf_(acc1[p][mt][r] + bi);
                const float ov = sigmoidf_(acc1[p + 2][mt][r] + bo);
                const float uv = tanhf_(acc1[p + 4][mt][r] + bu);
                float ci;
                if constexpr (LEAF) ci = 0.f;
                else ci = cin[ml * 264 + ch];
                const float cn = fmaf(iv, uv, ci);
                const float hn = ov * tanhf_(cn);
                const size_t m = (size_t)(m0 + ml);
                h_cur[m * HD + ch] = f2bf(hn);
                c_cur[m * HD + ch] = cn;
                if (level >= 6) hacc += hn;
                else atomicAdd(&hsum[((m0 + ml) >> level) * HD + ch], hn);
            }
        }
        if (level >= 6) atomicAdd(&hsum[(m0 >> level) * HD + ch], hacc);
    }
}

// out[tree][c] = (hsum[tree]/NPT) . lin_w[c] + lin_b[c]
__global__ __launch_bounds__(128) void final_kernel(
    const float* __restrict__ hsum, const float* __restrict__ lin_w,
    const float* __restrict__ lin_b, float* __restrict__ out)
{
    __shared__ float hg[HD];
    const int tree = blockIdx.x;
    for (int j = threadIdx.x; j < HD; j += 128)
        hg[j] = hsum[tree * HD + j] * (1.0f / (float)NPT);
    __syncthreads();
    const int c = threadIdx.x;
    if (c < NCLS) {
        const float* wr = lin_w + (size_t)c * HD;
        float acc = lin_b[c];
        #pragma unroll 4
        for (int j = 0; j < HD; ++j)
            acc = fmaf(hg[j], wr[j], acc);
        out[tree * NCLS + c] = acc;
    }
}

extern "C" void kernel_launch(void* const* d_in, const int* in_sizes, int n_in,
                              void* d_out, int out_size, void* d_ws, size_t ws_size,
                              hipStream_t stream)
{
    const int*   feat  = (const int*)d_in[0];
    const float* emb   = (const float*)d_in[1];
    const float* W_iou = (const float*)d_in[2];
    const float* U_iou = (const float*)d_in[3];
    const float* b_iou = (const float*)d_in[4];
    const float* U_f_w = (const float*)d_in[5];
    const float* U_f_b = (const float*)d_in[6];
    const float* lin_w = (const float*)d_in[7];
    const float* lin_b = (const float*)d_in[8];
    float* out = (float*)d_out;

    char* ws = (char*)d_ws;
    size_t off = 0;
    auto alloc = [&](size_t bytes) -> void* {
        void* p = ws + off;
        off += (bytes + 255) & ~(size_t)255;
        return p;
    };
    u16*   Wcat = (u16*)alloc((size_t)H3 * 512 * 2);
    u16*   Uf   = (u16*)alloc((size_t)HD * HD * 2);
    float* hsum = (float*)alloc((size_t)NTREES * HD * 4);
    u16*   hA   = (u16*)alloc((size_t)65536 * HD * 2);
    u16*   hB   = (u16*)alloc((size_t)32768 * HD * 2);
    float* cA   = (float*)alloc((size_t)65536 * HD * 4);
    float* cB   = (float*)alloc((size_t)32768 * HD * 4);
    (void)ws_size; (void)in_sizes; (void)n_in; (void)out_size;

    prep_weights<<<768, 256, 0, stream>>>(W_iou, U_iou, U_f_w, Wcat, Uf);
    hipMemsetAsync(hsum, 0, (size_t)NTREES * HD * 4, stream);

    for (int l = TDEPTH - 1; l >= 0; --l) {
        const int blocks = 1 << l;              // (64 << l) / 64
        const int p      = (TDEPTH - 1 - l) & 1;
        u16*   hc = p ? hB : hA;
        float* cc = p ? cB : cA;
        const u16*   hp = p ? hA : hB;
        const float* cp = p ? cA : cB;
        if (l == TDEPTH - 1) {
            level_kernel<true><<<blocks, 512, 0, stream>>>(
                feat, emb, Wcat, Uf, b_iou, U_f_b,
                nullptr, nullptr, hc, cc, hsum, l);
        } else {
            level_kernel<false><<<blocks, 512, 0, stream>>>(
                feat, emb, Wcat, Uf, b_iou, U_f_b,
                hp, cp, hc, cc, hsum, l);
        }
    }

    final_kernel<<<NTREES, 128, 0, stream>>>(hsum, lin_w, lin_b, out);
}